// Round 1
// baseline (4195.641 us; speedup 1.0000x reference)
//
#include <hip/hip_runtime.h>
#include <math.h>

#define NQ  4096      // queries
#define MB  100000    // bank rows
#define DD  512       // dim
#define QT  128       // query tile
#define BT  128       // bank tile
#define BK  32        // K step
#define KIT (DD / BK) // 16
#define NCH ((MB + BT - 1) / BT)  // 782 chunks

typedef __attribute__((ext_vector_type(8))) short short8;
typedef __attribute__((ext_vector_type(4))) float f32x4;

// ---- helpers --------------------------------------------------------------

// fp32 -> bf16 bits, round-to-nearest-even (no NaN handling needed; data is finite)
__device__ inline unsigned short f2bf(float f) {
  unsigned int u = __float_as_uint(f);
  u += 0x7FFFu + ((u >> 16) & 1u);
  return (unsigned short)(u >> 16);
}

// async global->LDS, 16B per lane. LDS dest must be wave-uniform-base + lane*16.
__device__ inline void gload_lds16(const void* g, void* l) {
  __builtin_amdgcn_global_load_lds(
      (const __attribute__((address_space(1))) unsigned int*)g,
      (__attribute__((address_space(3))) unsigned int*)l, 16, 0, 0);
}

struct Top2 { float v1, v2; int i1, i2; };

__device__ inline void t2ins(Top2& t, float v, int i) {
  if (v > t.v1 || (v == t.v1 && i < t.i1)) {
    t.v2 = t.v1; t.i2 = t.i1; t.v1 = v; t.i1 = i;
  } else if (v > t.v2 || (v == t.v2 && i < t.i2)) {
    t.v2 = v; t.i2 = i;
  }
}

// ---- kernel 1: L2-normalize rows and cast to bf16 -------------------------
// one wave per row; 8 f32 per lane
__global__ __launch_bounds__(256) void nrm_cast(const float* __restrict__ qin,
                                                const float* __restrict__ bin,
                                                unsigned short* __restrict__ qb,
                                                unsigned short* __restrict__ bb) {
  int wave = threadIdx.x >> 6, lane = threadIdx.x & 63;
  int row = blockIdx.x * 4 + wave;
  const float* src;
  unsigned short* dst;
  if (row < NQ) {
    src = qin + (size_t)row * DD;
    dst = qb + (size_t)row * DD;
  } else {
    int r2 = row - NQ;
    if (r2 >= MB) return;
    src = bin + (size_t)r2 * DD;
    dst = bb + (size_t)r2 * DD;
  }
  const float4* s4 = (const float4*)src;
  float4 x0 = s4[lane * 2], x1 = s4[lane * 2 + 1];
  float ss = x0.x * x0.x + x0.y * x0.y + x0.z * x0.z + x0.w * x0.w +
             x1.x * x1.x + x1.y * x1.y + x1.z * x1.z + x1.w * x1.w;
  for (int m = 1; m < 64; m <<= 1) ss += __shfl_xor(ss, m, 64);
  float r = 1.0f / fmaxf(sqrtf(ss), 1e-12f);  // matches max(||x||, EPS)
  short8 v;
  v[0] = (short)f2bf(x0.x * r); v[1] = (short)f2bf(x0.y * r);
  v[2] = (short)f2bf(x0.z * r); v[3] = (short)f2bf(x0.w * r);
  v[4] = (short)f2bf(x1.x * r); v[5] = (short)f2bf(x1.y * r);
  v[6] = (short)f2bf(x1.z * r); v[7] = (short)f2bf(x1.w * r);
  *(short8*)(dst + (size_t)lane * 8) = v;
}

// ---- kernel 2: bf16 MFMA GEMM (sims = Q · bank^T) with fused per-chunk top2
// grid = (NQ/QT, NCH); x fastest so consecutive blocks share a bank chunk (L2).
__global__ __launch_bounds__(256) void gemm_top2(const unsigned short* __restrict__ qb,
                                                 const unsigned short* __restrict__ bb,
                                                 float4* __restrict__ cand) {
  __shared__ unsigned short sA[QT * BK];  // 8 KB, row-major [128][32]
  __shared__ unsigned short sB[BT * BK];  // 8 KB
  int tid = threadIdx.x;
  int wave = tid >> 6, lane = tid & 63;
  int q0 = blockIdx.x * QT, c0 = blockIdx.y * BT;
  int wq = (wave >> 1) * 64, wb = (wave & 1) * 64;  // wave's 64x64 region

  f32x4 acc[4][4];
  for (int i = 0; i < 4; ++i)
    for (int j = 0; j < 4; ++j) acc[i][j] = (f32x4){0.f, 0.f, 0.f, 0.f};

  int sr = tid >> 2;             // staging row within 64-row half
  int ce = (tid & 3) * 8;        // staging col (elements)
  int br0 = c0 + sr;       if (br0 >= MB) br0 = MB - 1;  // clamp tail rows
  int br1 = c0 + 64 + sr;  if (br1 >= MB) br1 = MB - 1;

  int rr = lane & 15, kb = (lane >> 4) * 8;  // fragment row / k-block

  for (int kt = 0; kt < KIT; ++kt) {
    int kk = kt * BK;
    gload_lds16(qb + (size_t)(q0 + sr) * DD + kk + ce,      &sA[tid * 8]);
    gload_lds16(qb + (size_t)(q0 + 64 + sr) * DD + kk + ce, &sA[2048 + tid * 8]);
    gload_lds16(bb + (size_t)br0 * DD + kk + ce,            &sB[tid * 8]);
    gload_lds16(bb + (size_t)br1 * DD + kk + ce,            &sB[2048 + tid * 8]);
    __syncthreads();  // drains vmcnt

    short8 af[4], bg[4];
    for (int mi = 0; mi < 4; ++mi)
      af[mi] = *(const short8*)&sA[(wq + mi * 16 + rr) * BK + kb];
    for (int ni = 0; ni < 4; ++ni)
      bg[ni] = *(const short8*)&sB[(wb + ni * 16 + rr) * BK + kb];
    for (int mi = 0; mi < 4; ++mi)
      for (int ni = 0; ni < 4; ++ni)
        acc[mi][ni] = __builtin_amdgcn_mfma_f32_16x16x32_bf16(af[mi], bg[ni],
                                                              acc[mi][ni], 0, 0, 0);
    __syncthreads();  // all reads done before next stage overwrites
  }

  // epilogue: per-wave top2 per query row over its 64 columns
  // C layout (m89/m91): col = lane&15, row = (lane>>4)*4 + reg
  float4* mb = (float4*)sA;  // alias staging LDS: [128 rows][2 halves]
  int g = lane >> 4, cl = lane & 15;
  for (int mi = 0; mi < 4; ++mi) {
    for (int r2 = 0; r2 < 4; ++r2) {
      Top2 t; t.v1 = -__builtin_inff(); t.v2 = -__builtin_inff();
      t.i1 = 0x7fffffff; t.i2 = 0x7fffffff;
      for (int ni = 0; ni < 4; ++ni) {
        int col = c0 + wb + ni * 16 + cl;
        float v = acc[mi][ni][r2];
        if (col >= MB) v = -__builtin_inff();  // mask tail
        t2ins(t, v, col);
      }
      // butterfly across the 16 lanes sharing g (same q row)
      for (int m = 1; m <= 8; m <<= 1) {
        float ov1 = __shfl_xor(t.v1, m, 64); int oi1 = __shfl_xor(t.i1, m, 64);
        float ov2 = __shfl_xor(t.v2, m, 64); int oi2 = __shfl_xor(t.i2, m, 64);
        t2ins(t, ov1, oi1); t2ins(t, ov2, oi2);
      }
      if (cl == 0) {
        int ql = wq + mi * 16 + g * 4 + r2;
        mb[ql * 2 + (wave & 1)] =
            make_float4(t.v1, __int_as_float(t.i1), t.v2, __int_as_float(t.i2));
      }
    }
  }
  __syncthreads();

  if (tid < QT) {
    float4 a = mb[tid * 2], b = mb[tid * 2 + 1];
    Top2 t; t.v1 = a.x; t.i1 = __float_as_int(a.y);
    t.v2 = a.z; t.i2 = __float_as_int(a.w);
    t2ins(t, b.x, __float_as_int(b.y));
    t2ins(t, b.z, __float_as_int(b.w));
    cand[(size_t)(q0 + tid) * NCH + blockIdx.y] =
        make_float4(t.v1, __int_as_float(t.i1), t.v2, __int_as_float(t.i2));
  }
}

// ---- kernel 3: per-query candidate select + exact fp32 refine + gather ----
__global__ __launch_bounds__(256) void reduce_refine(
    const float* __restrict__ qraw, const float* __restrict__ braw,
    const int* __restrict__ cat, const int* __restrict__ shp,
    const float4* __restrict__ cand, int* __restrict__ out) {
  int q = blockIdx.x;
  int tid = threadIdx.x, wave = tid >> 6, lane = tid & 63;
  __shared__ float wmax[4];
  __shared__ int nsel;
  __shared__ int sel[64];
  __shared__ float rv[64];
  __shared__ int ri[64];
  if (tid == 0) nsel = 0;

  const float4* cq = cand + (size_t)q * NCH;
  float lm = -__builtin_inff();
  for (int c = tid; c < NCH; c += 256) lm = fmaxf(lm, cq[c].x);
  for (int m = 1; m < 64; m <<= 1) lm = fmaxf(lm, __shfl_xor(lm, m, 64));
  if (lane == 0) wmax[wave] = lm;
  __syncthreads();
  float M1 = fmaxf(fmaxf(wmax[0], wmax[1]), fmaxf(wmax[2], wmax[3]));
  float thr = M1 - 6e-3f;  // ~50 sigma of bf16 sim error; expect ~2 cands

  for (int c = tid; c < NCH; c += 256) {
    float4 e = cq[c];
    if (e.x >= thr) { int p = atomicAdd(&nsel, 1); if (p < 64) sel[p] = __float_as_int(e.y); }
    if (e.z >= thr) { int p = atomicAdd(&nsel, 1); if (p < 64) sel[p] = __float_as_int(e.w); }
  }
  __syncthreads();
  int ns = nsel; if (ns > 64) ns = 64;

  // exact fp32 refine from raw inputs (one candidate per wave)
  const float4* q4 = (const float4*)(qraw + (size_t)q * DD);
  float4 qa = q4[lane * 2], qv = q4[lane * 2 + 1];
  float qss = qa.x * qa.x + qa.y * qa.y + qa.z * qa.z + qa.w * qa.w +
              qv.x * qv.x + qv.y * qv.y + qv.z * qv.z + qv.w * qv.w;
  for (int m = 1; m < 64; m <<= 1) qss += __shfl_xor(qss, m, 64);
  float qn = fmaxf(sqrtf(qss), 1e-12f);

  for (int ci = wave; ci < ns; ci += 4) {
    int bi = sel[ci];
    const float4* b4 = (const float4*)(braw + (size_t)bi * DD);
    float4 ba = b4[lane * 2], bv = b4[lane * 2 + 1];
    float dot = qa.x * ba.x + qa.y * ba.y + qa.z * ba.z + qa.w * ba.w +
                qv.x * bv.x + qv.y * bv.y + qv.z * bv.z + qv.w * bv.w;
    float bss = ba.x * ba.x + ba.y * ba.y + ba.z * ba.z + ba.w * ba.w +
                bv.x * bv.x + bv.y * bv.y + bv.z * bv.z + bv.w * bv.w;
    for (int m = 1; m < 64; m <<= 1) {
      dot += __shfl_xor(dot, m, 64);
      bss += __shfl_xor(bss, m, 64);
    }
    if (lane == 0) {
      float bn = fmaxf(sqrtf(bss), 1e-12f);
      rv[ci] = dot / (qn * bn);
      ri[ci] = bi;
    }
  }
  __syncthreads();

  if (tid == 0) {
    float bvv = rv[0]; int bidx = ri[0];
    for (int i = 1; i < ns; ++i)
      if (rv[i] > bvv || (rv[i] == bvv && ri[i] < bidx)) { bvv = rv[i]; bidx = ri[i]; }
    out[q] = cat[bidx];
    out[NQ + q] = shp[bidx];
  }
}

// ---- launch ---------------------------------------------------------------
extern "C" void kernel_launch(void* const* d_in, const int* in_sizes, int n_in,
                              void* d_out, int out_size, void* d_ws, size_t ws_size,
                              hipStream_t stream) {
  const float* qin = (const float*)d_in[0];
  const float* bin = (const float*)d_in[1];
  const int* cat = (const int*)d_in[2];
  const int* shp = (const int*)d_in[3];
  int* out = (int*)d_out;

  // ws layout: qb (4 MB bf16) | bb (102.4 MB bf16) | cand (51.2 MB float4)
  char* ws = (char*)d_ws;
  unsigned short* qb = (unsigned short*)ws;
  unsigned short* bb = (unsigned short*)(ws + (size_t)NQ * DD * 2);
  float4* cand = (float4*)(ws + (size_t)NQ * DD * 2 + (size_t)MB * DD * 2);
  // total ws needed: 4194304 + 102400000 + 4096*782*16 = 157,843,456 bytes

  nrm_cast<<<(NQ + MB) / 4, 256, 0, stream>>>(qin, bin, qb, bb);
  gemm_top2<<<dim3(NQ / QT, NCH), 256, 0, stream>>>(qb, bb, cand);
  reduce_refine<<<NQ, 256, 0, stream>>>(qin, bin, cat, shp, cand, out);
}

// Round 2
// 1134.805 us; speedup vs baseline: 3.6972x; 3.6972x over previous
//
#include <hip/hip_runtime.h>
#include <math.h>

#define NQ  4096      // queries
#define MB  100000    // bank rows
#define DD  512       // dim
#define QT  128       // query tile
#define BT  128       // bank tile
#define BK  32        // K step
#define KIT (DD / BK) // 16
#define NCH ((MB + BT - 1) / BT)  // 782 chunks

typedef __attribute__((ext_vector_type(8))) short short8;
typedef __attribute__((ext_vector_type(4))) float f32x4;

// ---- helpers --------------------------------------------------------------

// fp32 -> bf16 bits, round-to-nearest-even
__device__ inline unsigned short f2bf(float f) {
  unsigned int u = __float_as_uint(f);
  u += 0x7FFFu + ((u >> 16) & 1u);
  return (unsigned short)(u >> 16);
}

// async global->LDS, 16B per lane. LDS dest must be wave-uniform-base + lane*16.
__device__ inline void gload_lds16(const void* g, void* l) {
  __builtin_amdgcn_global_load_lds(
      (const __attribute__((address_space(1))) unsigned int*)g,
      (__attribute__((address_space(3))) unsigned int*)l, 16, 0, 0);
}

struct Top2 { float v1, v2; int i1, i2; };

__device__ inline void t2ins(Top2& t, float v, int i) {
  if (v > t.v1 || (v == t.v1 && i < t.i1)) {
    t.v2 = t.v1; t.i2 = t.i1; t.v1 = v; t.i1 = i;
  } else if (v > t.v2 || (v == t.v2 && i < t.i2)) {
    t.v2 = v; t.i2 = i;
  }
}

// ---- kernel 1: L2-normalize rows and cast to bf16 -------------------------
__global__ __launch_bounds__(256) void nrm_cast(const float* __restrict__ qin,
                                                const float* __restrict__ bin,
                                                unsigned short* __restrict__ qb,
                                                unsigned short* __restrict__ bb) {
  int wave = threadIdx.x >> 6, lane = threadIdx.x & 63;
  int row = blockIdx.x * 4 + wave;
  const float* src;
  unsigned short* dst;
  if (row < NQ) {
    src = qin + (size_t)row * DD;
    dst = qb + (size_t)row * DD;
  } else {
    int r2 = row - NQ;
    if (r2 >= MB) return;
    src = bin + (size_t)r2 * DD;
    dst = bb + (size_t)r2 * DD;
  }
  const float4* s4 = (const float4*)src;
  float4 x0 = s4[lane * 2], x1 = s4[lane * 2 + 1];
  float ss = x0.x * x0.x + x0.y * x0.y + x0.z * x0.z + x0.w * x0.w +
             x1.x * x1.x + x1.y * x1.y + x1.z * x1.z + x1.w * x1.w;
  #pragma unroll
  for (int m = 1; m < 64; m <<= 1) ss += __shfl_xor(ss, m, 64);
  float r = 1.0f / fmaxf(sqrtf(ss), 1e-12f);
  short8 v;
  v[0] = (short)f2bf(x0.x * r); v[1] = (short)f2bf(x0.y * r);
  v[2] = (short)f2bf(x0.z * r); v[3] = (short)f2bf(x0.w * r);
  v[4] = (short)f2bf(x1.x * r); v[5] = (short)f2bf(x1.y * r);
  v[6] = (short)f2bf(x1.z * r); v[7] = (short)f2bf(x1.w * r);
  *(short8*)(dst + (size_t)lane * 8) = v;
}

// ---- kernel 2: bf16 MFMA GEMM with fused per-chunk top2 -------------------
// LDS tiles are XOR-swizzled (chunk slot = chunk ^ ((row>>2)&3)); the swizzle
// is applied on the GLOBAL source address (global_load_lds writes linearly)
// and the identical involution on the ds_read address (rule #21).
__global__ __launch_bounds__(256, 2) void gemm_top2(
    const unsigned short* __restrict__ qb,
    const unsigned short* __restrict__ bb,
    float4* __restrict__ cand) {
  __shared__ unsigned short sA[QT * BK];  // 8 KB
  __shared__ unsigned short sB[BT * BK];  // 8 KB
  int tid = threadIdx.x;
  int wave = tid >> 6, lane = tid & 63;
  int q0 = blockIdx.x * QT, c0 = blockIdx.y * BT;
  int wq = (wave >> 1) * 64, wb = (wave & 1) * 64;  // wave's 64x64 region

  f32x4 acc[4][4];
  #pragma unroll
  for (int i = 0; i < 4; ++i)
    #pragma unroll
    for (int j = 0; j < 4; ++j) acc[i][j] = (f32x4){0.f, 0.f, 0.f, 0.f};

  // staging decomposition: row within 64-row half, swizzled global chunk
  int sr = tid >> 2;                       // 0..63
  int slot = tid & 3;                      // LDS 16B slot within the row
  int swz = (tid >> 4) & 3;                // ((row>>2)&3), same for both halves
  int ce = (slot ^ swz) * 8;               // global chunk offset (elements)
  int br0 = c0 + sr;       if (br0 >= MB) br0 = MB - 1;
  int br1 = c0 + 64 + sr;  if (br1 >= MB) br1 = MB - 1;

  // fragment read decomposition
  int rr = lane & 15;                      // row within 16-row fragment
  int ck = lane >> 4;                      // k-chunk 0..3 (8 elems each)
  int rswz = (rr >> 2) & 3;                // read-side swizzle key
  int rco = ((ck ^ rswz) * 8);             // swizzled chunk offset (elements)

  for (int kt = 0; kt < KIT; ++kt) {
    int kk = kt * BK;
    gload_lds16(qb + (size_t)(q0 + sr) * DD + kk + ce,      &sA[tid * 8]);
    gload_lds16(qb + (size_t)(q0 + 64 + sr) * DD + kk + ce, &sA[2048 + tid * 8]);
    gload_lds16(bb + (size_t)br0 * DD + kk + ce,            &sB[tid * 8]);
    gload_lds16(bb + (size_t)br1 * DD + kk + ce,            &sB[2048 + tid * 8]);
    __syncthreads();  // drains vmcnt

    short8 af[4], bg[4];
    #pragma unroll
    for (int mi = 0; mi < 4; ++mi)
      af[mi] = *(const short8*)&sA[(wq + mi * 16 + rr) * BK + rco];
    #pragma unroll
    for (int ni = 0; ni < 4; ++ni)
      bg[ni] = *(const short8*)&sB[(wb + ni * 16 + rr) * BK + rco];
    #pragma unroll
    for (int mi = 0; mi < 4; ++mi)
      #pragma unroll
      for (int ni = 0; ni < 4; ++ni)
        acc[mi][ni] = __builtin_amdgcn_mfma_f32_16x16x32_bf16(af[mi], bg[ni],
                                                              acc[mi][ni], 0, 0, 0);
    __syncthreads();
  }

  // epilogue: per-wave top2 per query row over its 64 columns
  // C layout: col = lane&15, row = (lane>>4)*4 + reg
  float4* mb = (float4*)sA;  // alias staging LDS after last barrier
  int g = lane >> 4, cl = lane & 15;
  #pragma unroll
  for (int mi = 0; mi < 4; ++mi) {
    #pragma unroll
    for (int r2 = 0; r2 < 4; ++r2) {
      Top2 t; t.v1 = -__builtin_inff(); t.v2 = -__builtin_inff();
      t.i1 = 0x7fffffff; t.i2 = 0x7fffffff;
      #pragma unroll
      for (int ni = 0; ni < 4; ++ni) {
        int col = c0 + wb + ni * 16 + cl;
        float v = acc[mi][ni][r2];
        if (col >= MB) v = -__builtin_inff();
        t2ins(t, v, col);
      }
      #pragma unroll
      for (int m = 1; m <= 8; m <<= 1) {
        float ov1 = __shfl_xor(t.v1, m, 64); int oi1 = __shfl_xor(t.i1, m, 64);
        float ov2 = __shfl_xor(t.v2, m, 64); int oi2 = __shfl_xor(t.i2, m, 64);
        t2ins(t, ov1, oi1); t2ins(t, ov2, oi2);
      }
      if (cl == 0) {
        int ql = wq + mi * 16 + g * 4 + r2;
        mb[ql * 2 + (wave & 1)] =
            make_float4(t.v1, __int_as_float(t.i1), t.v2, __int_as_float(t.i2));
      }
    }
  }
  __syncthreads();

  if (tid < QT) {
    float4 a = mb[tid * 2], b = mb[tid * 2 + 1];
    Top2 t; t.v1 = a.x; t.i1 = __float_as_int(a.y);
    t.v2 = a.z; t.i2 = __float_as_int(a.w);
    t2ins(t, b.x, __float_as_int(b.y));
    t2ins(t, b.z, __float_as_int(b.w));
    cand[(size_t)(q0 + tid) * NCH + blockIdx.y] =
        make_float4(t.v1, __int_as_float(t.i1), t.v2, __int_as_float(t.i2));
  }
}

// ---- kernel 3: per-query candidate select + exact fp32 refine + gather ----
__global__ __launch_bounds__(256) void reduce_refine(
    const float* __restrict__ qraw, const float* __restrict__ braw,
    const int* __restrict__ cat, const int* __restrict__ shp,
    const float4* __restrict__ cand, int* __restrict__ out) {
  int q = blockIdx.x;
  int tid = threadIdx.x, wave = tid >> 6, lane = tid & 63;
  __shared__ float wmax[4];
  __shared__ int nsel;
  __shared__ int sel[64];
  __shared__ float rv[64];
  __shared__ int ri[64];
  if (tid == 0) nsel = 0;

  const float4* cq = cand + (size_t)q * NCH;
  float lm = -__builtin_inff();
  for (int c = tid; c < NCH; c += 256) lm = fmaxf(lm, cq[c].x);
  #pragma unroll
  for (int m = 1; m < 64; m <<= 1) lm = fmaxf(lm, __shfl_xor(lm, m, 64));
  if (lane == 0) wmax[wave] = lm;
  __syncthreads();
  float M1 = fmaxf(fmaxf(wmax[0], wmax[1]), fmaxf(wmax[2], wmax[3]));
  float thr = M1 - 6e-3f;  // ~50 sigma of bf16 sim error

  for (int c = tid; c < NCH; c += 256) {
    float4 e = cq[c];
    if (e.x >= thr) { int p = atomicAdd(&nsel, 1); if (p < 64) sel[p] = __float_as_int(e.y); }
    if (e.z >= thr) { int p = atomicAdd(&nsel, 1); if (p < 64) sel[p] = __float_as_int(e.w); }
  }
  __syncthreads();
  int ns = nsel; if (ns > 64) ns = 64;

  const float4* q4 = (const float4*)(qraw + (size_t)q * DD);
  float4 qa = q4[lane * 2], qv = q4[lane * 2 + 1];
  float qss = qa.x * qa.x + qa.y * qa.y + qa.z * qa.z + qa.w * qa.w +
              qv.x * qv.x + qv.y * qv.y + qv.z * qv.z + qv.w * qv.w;
  #pragma unroll
  for (int m = 1; m < 64; m <<= 1) qss += __shfl_xor(qss, m, 64);
  float qn = fmaxf(sqrtf(qss), 1e-12f);

  for (int ci = wave; ci < ns; ci += 4) {
    int bi = sel[ci];
    const float4* b4 = (const float4*)(braw + (size_t)bi * DD);
    float4 ba = b4[lane * 2], bv = b4[lane * 2 + 1];
    float dot = qa.x * ba.x + qa.y * ba.y + qa.z * ba.z + qa.w * ba.w +
                qv.x * bv.x + qv.y * bv.y + qv.z * bv.z + qv.w * bv.w;
    float bss = ba.x * ba.x + ba.y * ba.y + ba.z * ba.z + ba.w * ba.w +
                bv.x * bv.x + bv.y * bv.y + bv.z * bv.z + bv.w * bv.w;
    #pragma unroll
    for (int m = 1; m < 64; m <<= 1) {
      dot += __shfl_xor(dot, m, 64);
      bss += __shfl_xor(bss, m, 64);
    }
    if (lane == 0) {
      float bn = fmaxf(sqrtf(bss), 1e-12f);
      rv[ci] = dot / (qn * bn);
      ri[ci] = bi;
    }
  }
  __syncthreads();

  if (tid == 0) {
    float bvv = rv[0]; int bidx = ri[0];
    for (int i = 1; i < ns; ++i)
      if (rv[i] > bvv || (rv[i] == bvv && ri[i] < bidx)) { bvv = rv[i]; bidx = ri[i]; }
    out[q] = cat[bidx];
    out[NQ + q] = shp[bidx];
  }
}

// ---- launch ---------------------------------------------------------------
extern "C" void kernel_launch(void* const* d_in, const int* in_sizes, int n_in,
                              void* d_out, int out_size, void* d_ws, size_t ws_size,
                              hipStream_t stream) {
  const float* qin = (const float*)d_in[0];
  const float* bin = (const float*)d_in[1];
  const int* cat = (const int*)d_in[2];
  const int* shp = (const int*)d_in[3];
  int* out = (int*)d_out;

  char* ws = (char*)d_ws;
  unsigned short* qb = (unsigned short*)ws;
  unsigned short* bb = (unsigned short*)(ws + (size_t)NQ * DD * 2);
  float4* cand = (float4*)(ws + (size_t)NQ * DD * 2 + (size_t)MB * DD * 2);
  // total ws: 4 MB + 102.4 MB + 51.2 MB = 157,843,456 bytes

  nrm_cast<<<(NQ + MB) / 4, 256, 0, stream>>>(qin, bin, qb, bb);
  gemm_top2<<<dim3(NQ / QT, NCH), 256, 0, stream>>>(qb, bb, cand);
  reduce_refine<<<NQ, 256, 0, stream>>>(qin, bin, cat, shp, cand, out);
}

// Round 4
// 868.319 us; speedup vs baseline: 4.8319x; 1.3069x over previous
//
#include <hip/hip_runtime.h>
#include <math.h>

#define NQ  4096      // queries
#define MB  100000    // bank rows
#define DD  512       // dim
#define QT  128       // query tile (C cols)
#define BT  128       // bank tile  (C rows)
#define BK  32        // K step
#define KIT (DD / BK) // 16
#define NCH ((MB + BT - 1) / BT)  // 782 chunks
#define NWG (32 * NCH)            // 25024 blocks = 8 * 3128
#define MARGIN 6e-3f

typedef __attribute__((ext_vector_type(8))) short short8;
typedef __attribute__((ext_vector_type(4))) float f32x4;

__device__ inline unsigned int umax32(unsigned int a, unsigned int b) { return a > b ? a : b; }
__device__ inline unsigned int umin32(unsigned int a, unsigned int b) { return a < b ? a : b; }

// fp32 -> bf16 bits, round-to-nearest-even
__device__ inline unsigned short f2bf(float f) {
  unsigned int u = __float_as_uint(f);
  u += 0x7FFFu + ((u >> 16) & 1u);
  return (unsigned short)(u >> 16);
}

// async global->LDS, 16B per lane. LDS dest must be wave-uniform-base + lane*16.
__device__ inline void gload_lds16(const void* g, void* l) {
  __builtin_amdgcn_global_load_lds(
      (const __attribute__((address_space(1))) unsigned int*)g,
      (__attribute__((address_space(3))) unsigned int*)l, 16, 0, 0);
}

// ---- kernel 1: L2-normalize rows and cast to bf16 -------------------------
__global__ __launch_bounds__(256) void nrm_cast(const float* __restrict__ qin,
                                                const float* __restrict__ bin,
                                                unsigned short* __restrict__ qb,
                                                unsigned short* __restrict__ bb) {
  int wave = threadIdx.x >> 6, lane = threadIdx.x & 63;
  int row = blockIdx.x * 4 + wave;
  const float* src;
  unsigned short* dst;
  if (row < NQ) {
    src = qin + (size_t)row * DD;
    dst = qb + (size_t)row * DD;
  } else {
    int r2 = row - NQ;
    if (r2 >= MB) return;
    src = bin + (size_t)r2 * DD;
    dst = bb + (size_t)r2 * DD;
  }
  const float4* s4 = (const float4*)src;
  float4 x0 = s4[lane * 2], x1 = s4[lane * 2 + 1];
  float ss = x0.x * x0.x + x0.y * x0.y + x0.z * x0.z + x0.w * x0.w +
             x1.x * x1.x + x1.y * x1.y + x1.z * x1.z + x1.w * x1.w;
  #pragma unroll
  for (int m = 1; m < 64; m <<= 1) ss += __shfl_xor(ss, m, 64);
  float r = 1.0f / fmaxf(sqrtf(ss), 1e-12f);
  short8 v;
  v[0] = (short)f2bf(x0.x * r); v[1] = (short)f2bf(x0.y * r);
  v[2] = (short)f2bf(x0.z * r); v[3] = (short)f2bf(x0.w * r);
  v[4] = (short)f2bf(x1.x * r); v[5] = (short)f2bf(x1.y * r);
  v[6] = (short)f2bf(x1.z * r); v[7] = (short)f2bf(x1.w * r);
  *(short8*)(dst + (size_t)lane * 8) = v;
}

// ---- kernel 2: transposed bf16 MFMA GEMM (C = bank x query) + packed top2 -
// key u32 = (f32bits & ~127) | (127 - row_in_chunk); order-preserving for
// positive sims, ties break toward the smaller bank row. Chunk winners are
// always positive (max of 128 ~N(0,0.044) sims), negatives masked to key 0.
__global__ __launch_bounds__(256, 3) void gemm_top2(
    const unsigned short* __restrict__ qb,
    const unsigned short* __restrict__ bb,
    uint2* __restrict__ cand) {
  __shared__ unsigned short sM[2][BT * BK];  // bank tiles (dbuf) 2x8KB
  __shared__ unsigned short sN[2][QT * BK];  // query tiles (dbuf) 2x8KB
  __shared__ unsigned int rowwin[QT][2][2];  // [qcol][bank-half][k1,k2]  2KB

  int tid = threadIdx.x;
  int wave = tid >> 6, lane = tid & 63;

  // XCD-aware swizzle: 25024 = 8 * 3128, bijective
  int w = blockIdx.x;
  int sw = (w & 7) * (NWG / 8) + (w >> 3);
  int bx = sw & 31;       // q-tile 0..31 (fastest within an XCD's range)
  int by = sw >> 5;       // bank chunk 0..781
  int q0 = bx * QT, c0 = by * BT;
  int wm = (wave >> 1) * 64;  // bank-row half of this wave
  int wn = (wave & 1) * 64;   // q-col half of this wave

  f32x4 acc[4][4];
  #pragma unroll
  for (int i = 0; i < 4; ++i)
    #pragma unroll
    for (int j = 0; j < 4; ++j) acc[i][j] = (f32x4){0.f, 0.f, 0.f, 0.f};

  // staging decomposition (identical swizzle to the validated round-2 form)
  int sr = tid >> 2;             // row within 64-row half
  int slot = tid & 3;            // 16B slot within row
  int swz = (tid >> 4) & 3;      // (sr>>2)&3
  int ce = (slot ^ swz) * 8;     // swizzled global chunk offset (elements)
  int br0 = c0 + sr;       if (br0 >= MB) br0 = MB - 1;
  int br1 = c0 + 64 + sr;  if (br1 >= MB) br1 = MB - 1;

  // fragment read decomposition
  int rr = lane & 15;
  int ck = lane >> 4;
  int rco = (ck ^ ((rr >> 2) & 3)) * 8;

  const unsigned short* gM0 = bb + (size_t)br0 * DD + ce;
  const unsigned short* gM1 = bb + (size_t)br1 * DD + ce;
  const unsigned short* gN0 = qb + (size_t)(q0 + sr) * DD + ce;
  const unsigned short* gN1 = qb + (size_t)(q0 + 64 + sr) * DD + ce;

  auto STAGE = [&](int kt, int buf) {
    int kk = kt * BK;
    gload_lds16(gM0 + kk, &sM[buf][tid * 8]);
    gload_lds16(gM1 + kk, &sM[buf][2048 + tid * 8]);
    gload_lds16(gN0 + kk, &sN[buf][tid * 8]);
    gload_lds16(gN1 + kk, &sN[buf][2048 + tid * 8]);
  };

  STAGE(0, 0);
  __syncthreads();

  #pragma unroll 2
  for (int kt = 0; kt < KIT; ++kt) {
    int cur = kt & 1;
    if (kt + 1 < KIT) STAGE(kt + 1, cur ^ 1);  // prefetch overlaps compute

    const unsigned short* M0 = sM[cur];
    const unsigned short* N0 = sN[cur];
    short8 af[4], bg[4];
    #pragma unroll
    for (int mi = 0; mi < 4; ++mi)
      af[mi] = *(const short8*)&M0[(wm + mi * 16 + rr) * BK + rco];
    #pragma unroll
    for (int ni = 0; ni < 4; ++ni)
      bg[ni] = *(const short8*)&N0[(wn + ni * 16 + rr) * BK + rco];
    #pragma unroll
    for (int mi = 0; mi < 4; ++mi)
      #pragma unroll
      for (int ni = 0; ni < 4; ++ni)
        acc[mi][ni] = __builtin_amdgcn_mfma_f32_16x16x32_bf16(af[mi], bg[ni],
                                                              acc[mi][ni], 0, 0, 0);
    __syncthreads();  // drains prefetch vmcnt AFTER compute; guards buffer swap
  }

  // ---- epilogue: packed-key top2 per query col over 128 bank rows ---------
  // C layout: col = lane&15 (+ni*16+wn), row = (lane>>4)*4 + reg (+mi*16+wm)
  int g = lane >> 4, cl = lane & 15;
  bool tail = (c0 + BT > MB);
  int nb = 127 - wm - g * 4;  // 127 - row_in_chunk base
  unsigned int K1[4], K2[4];
  #pragma unroll
  for (int ni = 0; ni < 4; ++ni) { K1[ni] = 0u; K2[ni] = 0u; }

  #pragma unroll
  for (int mi = 0; mi < 4; ++mi) {
    #pragma unroll
    for (int r2 = 0; r2 < 4; ++r2) {
      int rowoff = mi * 16 + r2;
      #pragma unroll
      for (int ni = 0; ni < 4; ++ni) {
        float v = acc[mi][ni][r2];
        unsigned int key = (__float_as_uint(v) & 0xFFFFFF80u) |
                           (unsigned int)(nb - rowoff);
        bool ok = v > 0.0f;
        if (tail) ok = ok && (c0 + wm + g * 4 + rowoff < MB);
        key = ok ? key : 0u;
        unsigned int mx = umax32(K1[ni], key), mn = umin32(K1[ni], key);
        K1[ni] = mx;
        K2[ni] = umax32(K2[ni], mn);
      }
    }
  }

  // 2-step butterfly across the 4 lanes (xor 16, 32) sharing each q col
  #pragma unroll
  for (int m = 16; m <= 32; m <<= 1) {
    #pragma unroll
    for (int ni = 0; ni < 4; ++ni) {
      unsigned int o1 = (unsigned int)__shfl_xor((int)K1[ni], m, 64);
      unsigned int o2 = (unsigned int)__shfl_xor((int)K2[ni], m, 64);
      unsigned int mx = umax32(K1[ni], o1), mn = umin32(K1[ni], o1);
      K1[ni] = mx;
      K2[ni] = umax32(mn, umax32(K2[ni], o2));
    }
  }
  if (g == 0) {
    #pragma unroll
    for (int ni = 0; ni < 4; ++ni) {
      int qc = wn + ni * 16 + cl;
      rowwin[qc][wave >> 1][0] = K1[ni];
      rowwin[qc][wave >> 1][1] = K2[ni];
    }
  }
  __syncthreads();

  if (tid < QT) {
    unsigned int a1 = rowwin[tid][0][0], a2 = rowwin[tid][0][1];
    unsigned int b1 = rowwin[tid][1][0], b2 = rowwin[tid][1][1];
    unsigned int k1 = umax32(a1, b1);
    unsigned int k2 = umax32(umin32(a1, b1), umax32(a2, b2));
    // cand layout [chunk][query] -> coalesced 1KB store per block
    cand[(size_t)by * NQ + q0 + tid] = make_uint2(k1, k2);
  }
}

// ---- kernel 3: per-query candidate select + exact fp32 refine + gather ----
__global__ __launch_bounds__(256) void reduce_refine(
    const float* __restrict__ qraw, const float* __restrict__ braw,
    const int* __restrict__ cat, const int* __restrict__ shp,
    const uint2* __restrict__ cand, int* __restrict__ out) {
  int q = blockIdx.x;
  int tid = threadIdx.x, wave = tid >> 6, lane = tid & 63;
  __shared__ unsigned int wmax[4];
  __shared__ int nsel;
  __shared__ int sel[64];
  __shared__ float rv[64];
  __shared__ int ri[64];
  if (tid == 0) nsel = 0;

  // pass 1: max key (value ordering; low 7 bits are only tie-break noise)
  unsigned int mk = 0;
  for (int c = tid; c < NCH; c += 256) mk = umax32(mk, cand[(size_t)c * NQ + q].x);
  #pragma unroll
  for (int m = 1; m < 64; m <<= 1)
    mk = umax32(mk, (unsigned int)__shfl_xor((int)mk, m, 64));
  if (lane == 0) wmax[wave] = mk;
  __syncthreads();
  unsigned int M1 = umax32(umax32(wmax[0], wmax[1]), umax32(wmax[2], wmax[3]));
  float thr = __uint_as_float(M1 & 0xFFFFFF80u) - MARGIN;

  // pass 2: select candidates within margin (L2-hot re-read)
  for (int c = tid; c < NCH; c += 256) {
    uint2 e = cand[(size_t)c * NQ + q];
    float f1 = __uint_as_float(e.x & 0xFFFFFF80u);
    float f2 = __uint_as_float(e.y & 0xFFFFFF80u);
    if (f1 >= thr) {
      int p = atomicAdd(&nsel, 1);
      if (p < 64) sel[p] = c * BT + 127 - (int)(e.x & 127u);
    }
    if (f2 >= thr) {
      int p = atomicAdd(&nsel, 1);
      if (p < 64) sel[p] = c * BT + 127 - (int)(e.y & 127u);
    }
  }
  __syncthreads();
  int ns = nsel; if (ns > 64) ns = 64;

  // exact fp32 refine from raw inputs (one candidate per wave)
  const float4* q4 = (const float4*)(qraw + (size_t)q * DD);
  float4 qa = q4[lane * 2], qv = q4[lane * 2 + 1];
  float qss = qa.x * qa.x + qa.y * qa.y + qa.z * qa.z + qa.w * qa.w +
              qv.x * qv.x + qv.y * qv.y + qv.z * qv.z + qv.w * qv.w;
  #pragma unroll
  for (int m = 1; m < 64; m <<= 1) qss += __shfl_xor(qss, m, 64);
  float qn = fmaxf(sqrtf(qss), 1e-12f);

  for (int ci = wave; ci < ns; ci += 4) {
    int bi = sel[ci];
    const float4* b4 = (const float4*)(braw + (size_t)bi * DD);
    float4 ba = b4[lane * 2], bv = b4[lane * 2 + 1];
    float dot = qa.x * ba.x + qa.y * ba.y + qa.z * ba.z + qa.w * ba.w +
                qv.x * bv.x + qv.y * bv.y + qv.z * bv.z + qv.w * bv.w;
    float bss = ba.x * ba.x + ba.y * ba.y + ba.z * ba.z + ba.w * ba.w +
                bv.x * bv.x + bv.y * bv.y + bv.z * bv.z + bv.w * bv.w;
    #pragma unroll
    for (int m = 1; m < 64; m <<= 1) {
      dot += __shfl_xor(dot, m, 64);
      bss += __shfl_xor(bss, m, 64);
    }
    if (lane == 0) {
      float bn = fmaxf(sqrtf(bss), 1e-12f);
      rv[ci] = dot / (qn * bn);
      ri[ci] = bi;
    }
  }
  __syncthreads();

  if (tid == 0) {
    float bvv = rv[0]; int bidx = ri[0];
    for (int i = 1; i < ns; ++i)
      if (rv[i] > bvv || (rv[i] == bvv && ri[i] < bidx)) { bvv = rv[i]; bidx = ri[i]; }
    out[q] = cat[bidx];
    out[NQ + q] = shp[bidx];
  }
}

// ---- launch ---------------------------------------------------------------
extern "C" void kernel_launch(void* const* d_in, const int* in_sizes, int n_in,
                              void* d_out, int out_size, void* d_ws, size_t ws_size,
                              hipStream_t stream) {
  const float* qin = (const float*)d_in[0];
  const float* bin = (const float*)d_in[1];
  const int* cat = (const int*)d_in[2];
  const int* shp = (const int*)d_in[3];
  int* out = (int*)d_out;

  char* ws = (char*)d_ws;
  unsigned short* qb = (unsigned short*)ws;
  unsigned short* bb = (unsigned short*)(ws + (size_t)NQ * DD * 2);
  uint2* cand = (uint2*)(ws + (size_t)NQ * DD * 2 + (size_t)MB * DD * 2);
  // ws: 4 MB (qb) + 102.4 MB (bb) + 25.6 MB (cand) = 132 MB

  nrm_cast<<<(NQ + MB) / 4, 256, 0, stream>>>(qin, bin, qb, bb);
  gemm_top2<<<NWG, 256, 0, stream>>>(qb, bb, cand);
  reduce_refine<<<NQ, 256, 0, stream>>>(qin, bin, cat, shp, cand, out);
}